// Round 6
// baseline (229.178 us; speedup 1.0000x reference)
//
#include <hip/hip_runtime.h>

#define BATCH   2
#define SEQ     2048
#define DMODEL  1024
#define NHEADS  16
#define DHEAD   64
#define NGROUPS 8
#define NTOK    (BATCH * SEQ)   // 4096
#define QKV_N   2048            // 1024 Q | 512 K | 512 V

typedef unsigned short ushort_t;
typedef unsigned int u32;
typedef __attribute__((ext_vector_type(8))) short short8;
typedef __attribute__((ext_vector_type(4))) float f32x4;
typedef __attribute__((ext_vector_type(16))) float f32x16;

#define MFMA16(a, b, c) __builtin_amdgcn_mfma_f32_16x16x32_bf16((a), (b), (c), 0, 0, 0)
#define MFMA32(a, b, c) __builtin_amdgcn_mfma_f32_32x32x16_bf16((a), (b), (c), 0, 0, 0)

// async global->LDS, 16B per lane, LDS dest = wave-uniform base + lane*16
#define GLOAD16(gp, lp)                                                        \
    __builtin_amdgcn_global_load_lds(                                          \
        (const u32 __attribute__((address_space(1)))*)(gp),                    \
        (u32 __attribute__((address_space(3)))*)(lp), 16, 0, 0)

__device__ __forceinline__ ushort_t f2bu(float x) {
    unsigned u = __builtin_bit_cast(unsigned, x);
    unsigned r = (u + 0x7fffu + ((u >> 16) & 1u)) >> 16;   // RNE
    return (ushort_t)r;
}

// ---------------------------------------------------------------------------
// Prep 1: resid f32 -> bf16
// ---------------------------------------------------------------------------
__global__ __launch_bounds__(256) void cvt_resid(
    const float* __restrict__ in, ushort_t* __restrict__ out)
{
    const int i4 = blockIdx.x * 256 + threadIdx.x;
    union { float4 v; float f[4]; } a;
    a.v = *reinterpret_cast<const float4*>(in + (size_t)i4 * 4);
    union { uint2 v; ushort_t u[4]; } o;
    #pragma unroll
    for (int j = 0; j < 4; ++j) o.u[j] = f2bu(a.f[j]);
    *reinterpret_cast<uint2*>(out + (size_t)i4 * 4) = o.v;
}

// ---------------------------------------------------------------------------
// Prep 2: Wt[n=2048][k=1024] bf16 (n-major) from W_Q|W_K|W_V (f32, k-major)
// ---------------------------------------------------------------------------
__global__ __launch_bounds__(256) void tr_wqkv(
    const float* __restrict__ Wq, const float* __restrict__ Wk,
    const float* __restrict__ Wv, ushort_t* __restrict__ Wt)
{
    __shared__ float Ws[64][65];
    const int t  = threadIdx.x;
    const int k0 = blockIdx.x * 64;
    const int n0 = blockIdx.y * 64;

    const float* src; int stride, boff;
    if (n0 < 1024)       { src = Wq; stride = 1024; boff = n0; }
    else if (n0 < 1536)  { src = Wk; stride = 512;  boff = n0 - 1024; }
    else                 { src = Wv; stride = 512;  boff = n0 - 1536; }

    #pragma unroll
    for (int i = 0; i < 4; ++i) {
        const int c = i * 256 + t;
        const int row = c >> 4, cc = (c & 15) * 4;
        union { float4 v; float f[4]; } a;
        a.v = *reinterpret_cast<const float4*>(src + (size_t)(k0 + row) * stride + boff + cc);
        #pragma unroll
        for (int j = 0; j < 4; ++j) Ws[row][cc + j] = a.f[j];
    }
    __syncthreads();
    #pragma unroll
    for (int i = 0; i < 2; ++i) {
        const int c = i * 256 + t;
        const int nr = c >> 3, kc = (c & 7) * 8;
        union { uint4 v; ushort_t u[8]; } o;
        #pragma unroll
        for (int j = 0; j < 8; ++j) o.u[j] = f2bu(Ws[kc + j][nr]);
        *reinterpret_cast<uint4*>(Wt + (size_t)(n0 + nr) * 1024 + k0 + kc) = o.v;
    }
}

// ---------------------------------------------------------------------------
// Prep 3: Wout_t[d=1024][j=h*64+e] bf16 from W_out[e][h][d] f32
// ---------------------------------------------------------------------------
__global__ __launch_bounds__(256) void tr_wout(
    const float* __restrict__ Wout, ushort_t* __restrict__ Wt)
{
    __shared__ float Ws[64][65];
    const int t  = threadIdx.x;
    const int d0 = blockIdx.x * 64;
    const int h  = blockIdx.y;

    #pragma unroll
    for (int i = 0; i < 4; ++i) {
        const int c = i * 256 + t;
        const int e = c >> 4, dd = (c & 15) * 4;
        union { float4 v; float f[4]; } a;
        a.v = *reinterpret_cast<const float4*>(Wout + (size_t)(e * 16 + h) * 1024 + d0 + dd);
        #pragma unroll
        for (int j = 0; j < 4; ++j) Ws[e][dd + j] = a.f[j];
    }
    __syncthreads();
    #pragma unroll
    for (int i = 0; i < 2; ++i) {
        const int c = i * 256 + t;
        const int dr = c >> 3, ec = (c & 7) * 8;
        union { uint4 v; ushort_t u[8]; } o;
        #pragma unroll
        for (int j = 0; j < 8; ++j) o.u[j] = f2bu(Ws[ec + j][dr]);
        *reinterpret_cast<uint4*>(Wt + (size_t)(d0 + dr) * 1024 + h * 64 + ec) = o.v;
    }
}

// ---------------------------------------------------------------------------
// Prep 4 (after qkv_gemm): Vt[b][g][e][s] bf16 from qkv V slab.
// ---------------------------------------------------------------------------
__global__ __launch_bounds__(256) void tr_v(
    const ushort_t* __restrict__ qkv, ushort_t* __restrict__ Vt)
{
    __shared__ ushort_t T[64][72];
    const int t  = threadIdx.x;
    const int s0 = blockIdx.x * 64;
    const int g  = blockIdx.y;
    const int b  = blockIdx.z;

    #pragma unroll
    for (int i = 0; i < 2; ++i) {
        const int c = i * 256 + t;
        const int row = c >> 3, ec = (c & 7) * 8;
        *reinterpret_cast<uint4*>(&T[row][ec]) =
            *reinterpret_cast<const uint4*>(
                qkv + (size_t)(b * SEQ + s0 + row) * QKV_N + 1536 + g * 64 + ec);
    }
    __syncthreads();
    #pragma unroll
    for (int i = 0; i < 2; ++i) {
        const int c = i * 256 + t;
        const int er = c >> 3, sc = (c & 7) * 8;
        union { uint4 v; ushort_t u[8]; } o;
        #pragma unroll
        for (int j = 0; j < 8; ++j) o.u[j] = T[sc + j][er];
        *reinterpret_cast<uint4*>(
            Vt + (size_t)((b * NGROUPS + g) * 64 + er) * SEQ + s0 + sc) = o.v;
    }
}

// ---------------------------------------------------------------------------
// MFMA GEMM (m97-style): 128x128 tile, BK=32, global_load_lds width 16,
// XOR-swizzled 16B chunks -> <=4-way on fragment reads.
// ---------------------------------------------------------------------------
__global__ __launch_bounds__(256) void qkv_gemm(
    const ushort_t* __restrict__ A, const ushort_t* __restrict__ Bt,
    ushort_t* __restrict__ C)
{
    __shared__ ushort_t As[128][32];
    __shared__ ushort_t Bs[128][32];

    const int t = threadIdx.x;
    const int wave = t >> 6, lane = t & 63;
    const int quad = lane >> 4, x = lane & 15;
    const int wm = (wave >> 1) * 64, wn = (wave & 1) * 64;
    const int m0 = blockIdx.y * 128, n0 = blockIdx.x * 128;

    const int sr = lane >> 2;
    const int gc = (lane & 3) ^ (sr & 3);

    f32x4 acc[4][4];
    #pragma unroll
    for (int i = 0; i < 4; ++i)
        #pragma unroll
        for (int j = 0; j < 4; ++j) acc[i][j] = (f32x4)(0.f);

    const int swz = (quad ^ (x & 3)) * 8;

    for (int k0 = 0; k0 < 1024; k0 += 32) {
        #pragma unroll
        for (int s = 0; s < 2; ++s) {
            const int r0 = (wave * 2 + s) * 16;
            GLOAD16(A  + (size_t)(m0 + r0 + sr) * 1024 + k0 + gc * 8, &As[r0][0]);
            GLOAD16(Bt + (size_t)(n0 + r0 + sr) * 1024 + k0 + gc * 8, &Bs[r0][0]);
        }
        __syncthreads();
        short8 af[4], bf[4];
        #pragma unroll
        for (int mt = 0; mt < 4; ++mt)
            af[mt] = *reinterpret_cast<const short8*>(&As[wm + mt * 16 + x][swz]);
        #pragma unroll
        for (int nt = 0; nt < 4; ++nt)
            bf[nt] = *reinterpret_cast<const short8*>(&Bs[wn + nt * 16 + x][swz]);
        #pragma unroll
        for (int mt = 0; mt < 4; ++mt)
            #pragma unroll
            for (int nt = 0; nt < 4; ++nt)
                acc[mt][nt] = MFMA16(af[mt], bf[nt], acc[mt][nt]);
        __syncthreads();
    }

    #pragma unroll
    for (int mt = 0; mt < 4; ++mt)
        #pragma unroll
        for (int nt = 0; nt < 4; ++nt)
            #pragma unroll
            for (int r = 0; r < 4; ++r) {
                const int row = m0 + wm + mt * 16 + quad * 4 + r;
                const int col = n0 + wn + nt * 16 + x;
                C[(size_t)row * QKV_N + col] = f2bu(acc[mt][nt][r]);
            }
}

__global__ __launch_bounds__(256) void out_gemm(
    const ushort_t* __restrict__ A, const ushort_t* __restrict__ Bt,
    const float* __restrict__ bias, float* __restrict__ C)
{
    __shared__ ushort_t As[128][32];
    __shared__ ushort_t Bs[128][32];

    const int t = threadIdx.x;
    const int wave = t >> 6, lane = t & 63;
    const int quad = lane >> 4, x = lane & 15;
    const int wm = (wave >> 1) * 64, wn = (wave & 1) * 64;
    const int m0 = blockIdx.y * 128, n0 = blockIdx.x * 128;

    const int sr = lane >> 2;
    const int gc = (lane & 3) ^ (sr & 3);

    f32x4 acc[4][4];
    #pragma unroll
    for (int i = 0; i < 4; ++i)
        #pragma unroll
        for (int j = 0; j < 4; ++j) acc[i][j] = (f32x4)(0.f);

    const int swz = (quad ^ (x & 3)) * 8;

    for (int k0 = 0; k0 < 1024; k0 += 32) {
        #pragma unroll
        for (int s = 0; s < 2; ++s) {
            const int r0 = (wave * 2 + s) * 16;
            GLOAD16(A  + (size_t)(m0 + r0 + sr) * 1024 + k0 + gc * 8, &As[r0][0]);
            GLOAD16(Bt + (size_t)(n0 + r0 + sr) * 1024 + k0 + gc * 8, &Bs[r0][0]);
        }
        __syncthreads();
        short8 af[4], bf[4];
        #pragma unroll
        for (int mt = 0; mt < 4; ++mt)
            af[mt] = *reinterpret_cast<const short8*>(&As[wm + mt * 16 + x][swz]);
        #pragma unroll
        for (int nt = 0; nt < 4; ++nt)
            bf[nt] = *reinterpret_cast<const short8*>(&Bs[wn + nt * 16 + x][swz]);
        #pragma unroll
        for (int mt = 0; mt < 4; ++mt)
            #pragma unroll
            for (int nt = 0; nt < 4; ++nt)
                acc[mt][nt] = MFMA16(af[mt], bf[nt], acc[mt][nt]);
        __syncthreads();
    }

    float bv[4];
    #pragma unroll
    for (int nt = 0; nt < 4; ++nt) bv[nt] = bias[n0 + wn + nt * 16 + x];

    #pragma unroll
    for (int mt = 0; mt < 4; ++mt)
        #pragma unroll
        for (int nt = 0; nt < 4; ++nt)
            #pragma unroll
            for (int r = 0; r < 4; ++r) {
                const int row = m0 + wm + mt * 16 + quad * 4 + r;
                const int col = n0 + wn + nt * 16 + x;
                C[(size_t)row * 1024 + col] = acc[mt][nt][r] + bv[nt];
            }
}

// ---------------------------------------------------------------------------
// MFMA flash attention, v5 (32x32x16):
//  - block = (qp, h, b); waves 0,1 -> q-tile 31-qp (rows w*32), waves 2,3 ->
//    q-tile qp; single kt loop 0..31-qp, K/V staged once for both tiles
//  - S computed TRANSPOSED (K as A, Q as B) so probs pack into b64 LDS
//    writes and PV reads them as b128 A-fragments
//  - 16B-chunk XOR swizzle (chunk ^= (row>>3)&3) on all LDS tiles
//  - max-free softmax, l from truncated-bf16 probs (bias cancels in O/l)
// ---------------------------------------------------------------------------
__global__ __launch_bounds__(256) void attn(
    const ushort_t* __restrict__ qkv, const ushort_t* __restrict__ Vt,
    ushort_t* __restrict__ z)
{
    __shared__ ushort_t Qs[128][72];   // [local qrow][e]
    __shared__ ushort_t Ks[64][72];    // [key][e]
    __shared__ ushort_t Vts[64][72];   // [e][key]
    __shared__ ushort_t Pl[128][72];   // [local qrow][key]
    __shared__ float    linv[128];

    const int t = threadIdx.x;
    const int wave = t >> 6, lane = t & 63;
    const int l5 = lane >> 5;          // 0/1
    const int lm = lane & 31;
    const int qp = blockIdx.x;         // 0..15, qp=0 heaviest (dispatched first)
    const int h  = blockIdx.y;
    const int b  = blockIdx.z;
    const int g  = h >> 1;
    const int qt1 = 31 - qp;                       // heavy tile
    const int my_qt = (wave < 2) ? qt1 : qp;
    const int lrow0 = wave * 32;                   // local row base (Qs/Pl)
    const int grow0 = my_qt * 64 + (wave & 1) * 32;
    const int qlocal = (wave & 1) * 32 + lm;       // q-row within my 64-tile

    const int srow = t >> 3;           // 0..31 (staging row; +32 for 2nd pass)
    const int sgc  = t & 7;            // staging 16B chunk

    // ---- stage Q: local rows [0,64)=tile qt1, [64,128)=tile qp ----
    #pragma unroll
    for (int i = 0; i < 4; ++i) {
        const int row = srow + i * 32;
        const int grow = (row < 64) ? (qt1 * 64 + row) : (qp * 64 + row - 64);
        const int lc = sgc ^ ((row >> 3) & 3);
        *reinterpret_cast<uint4*>(&Qs[row][lc * 8]) =
            *reinterpret_cast<const uint4*>(
                qkv + (size_t)(b * SEQ + grow) * QKV_N + h * DHEAD + sgc * 8);
    }
    __syncthreads();

    // ---- hoist Q B-fragments (constant for all kt) ----
    short8 qf[4];
    {
        const int row = lrow0 + lm;
        const int sw = (row >> 3) & 3;
        #pragma unroll
        for (int ks = 0; ks < 4; ++ks) {
            const int c = (2 * ks + l5) ^ sw;
            qf[ks] = *reinterpret_cast<const short8*>(&Qs[row][c * 8]);
        }
    }

    f32x16 o0 = (f32x16)(0.f), o1 = (f32x16)(0.f);
    float l_acc = 0.f;

    const ushort_t* kg = qkv + (size_t)b * SEQ * QKV_N + 1024 + g * DHEAD + sgc * 8;
    const ushort_t* vg = Vt + ((size_t)(b * NGROUPS + g) * 64) * SEQ + sgc * 8;

    uint4 kr[2], vr[2];
    #pragma unroll
    for (int i = 0; i < 2; ++i) {
        const int row = srow + i * 32;
        kr[i] = *reinterpret_cast<const uint4*>(kg + (size_t)row * QKV_N);
        vr[i] = *reinterpret_cast<const uint4*>(vg + (size_t)row * SEQ);
    }

    const int ktmax = qt1;
    for (int kt = 0; kt <= ktmax; ++kt) {
        __syncthreads();
        #pragma unroll
        for (int i = 0; i < 2; ++i) {
            const int row = srow + i * 32;
            const int lc = sgc ^ ((row >> 3) & 3);
            *reinterpret_cast<uint4*>(&Ks[row][lc * 8])  = kr[i];
            *reinterpret_cast<uint4*>(&Vts[row][lc * 8]) = vr[i];
        }
        __syncthreads();

        if (kt < ktmax) {   // prefetch next K/V tile (overlaps compute)
            #pragma unroll
            for (int i = 0; i < 2; ++i) {
                const int row = srow + i * 32;
                kr[i] = *reinterpret_cast<const uint4*>(
                    kg + (size_t)((kt + 1) * 64 + row) * QKV_N);
                vr[i] = *reinterpret_cast<const uint4*>(
                    vg + (size_t)row * SEQ + (kt + 1) * 64);
            }
        }

        if (kt <= my_qt) {
            const bool diag = (kt == my_qt);
            const int nmt = diag ? ((wave & 1) + 1) : 2;   // valid 32-key m-tiles
            const int swp = ((lrow0 + lm) >> 3) & 3;

            for (int mt = 0; mt < nmt; ++mt) {
                f32x16 s = (f32x16)(0.f);
                const int krow = mt * 32 + lm;
                const int swk = (krow >> 3) & 3;
                #pragma unroll
                for (int ks = 0; ks < 4; ++ks) {
                    const int c = (2 * ks + l5) ^ swk;
                    short8 kf = *reinterpret_cast<const short8*>(&Ks[krow][c * 8]);
                    s = MFMA32(kf, qf[ks], s);   // S^T[key][qrow]
                }
                // exp + truncate-pack + b64 Pl write
                #pragma unroll
                for (int rg = 0; rg < 4; ++rg) {
                    unsigned packed[2];
                    #pragma unroll
                    for (int jp = 0; jp < 2; ++jp) {
                        unsigned lo = 0, hi = 0;
                        #pragma unroll
                        for (int jj = 0; jj < 2; ++jj) {
                            const int j = jp * 2 + jj;
                            float p = __expf(s[rg * 4 + j] * 0.125f);
                            if (diag) {
                                const int klocal = mt * 32 + j + 8 * rg + 4 * l5;
                                if (klocal > qlocal) p = 0.f;
                            }
                            const unsigned pu =
                                __builtin_bit_cast(unsigned, p) & 0xffff0000u;
                            l_acc += __builtin_bit_cast(float, pu);
                            if (jj == 0) lo = pu >> 16; else hi = pu;
                        }
                        packed[jp] = lo | hi;
                    }
                    const int c16 = (mt * 4 + rg) ^ swp;
                    *reinterpret_cast<uint2*>(&Pl[lrow0 + lm][c16 * 8 + l5 * 4]) =
                        make_uint2(packed[0], packed[1]);
                }
            }

            // PV: O[q][e] += P[q][key] . V[key][e]
            const int nks = 2 * nmt;
            const int prow = lrow0 + lm;
            for (int ks = 0; ks < nks; ++ks) {
                const int cp = (2 * ks + l5) ^ swp;
                short8 ap = *reinterpret_cast<const short8*>(&Pl[prow][cp * 8]);
                {
                    const int cv = (2 * ks + l5) ^ ((lm >> 3) & 3);
                    short8 vf = *reinterpret_cast<const short8*>(&Vts[lm][cv * 8]);
                    o0 = MFMA32(ap, vf, o0);
                }
                {
                    const int vrow = 32 + lm;
                    const int cv = (2 * ks + l5) ^ ((vrow >> 3) & 3);
                    short8 vf = *reinterpret_cast<const short8*>(&Vts[vrow][cv * 8]);
                    o1 = MFMA32(ap, vf, o1);
                }
            }
        }
    }

    // ---- epilogue: finish l, normalize, store z ----
    {
        const float l = l_acc + __shfl_xor(l_acc, 32);
        if (lane < 32) linv[lrow0 + lane] = 1.f / l;
    }
    __syncthreads();
    #pragma unroll
    for (int reg = 0; reg < 16; ++reg) {
        const int lr = (reg & 3) + 8 * (reg >> 2) + 4 * l5;
        const float inv = linv[lrow0 + lr];
        const size_t rowbase = (size_t)(b * SEQ + grow0 + lr) * 1024 + h * DHEAD;
        z[rowbase + lm]      = f2bu(o0[reg] * inv);
        z[rowbase + 32 + lm] = f2bu(o1[reg] * inv);
    }
}

// ---------------------------------------------------------------------------
extern "C" void kernel_launch(void* const* d_in, const int* in_sizes, int n_in,
                              void* d_out, int out_size, void* d_ws, size_t ws_size,
                              hipStream_t stream)
{
    const float* resid = (const float*)d_in[0];
    const float* Wq    = (const float*)d_in[1];
    const float* Wk    = (const float*)d_in[2];
    const float* Wv    = (const float*)d_in[3];
    const float* Wout  = (const float*)d_in[4];
    const float* bout  = (const float*)d_in[5];
    float* out = (float*)d_out;

    ushort_t* rbf   = (ushort_t*)d_ws;                       //  8 MB  [4096][1024]
    ushort_t* wqkvt = rbf   + (size_t)NTOK * DMODEL;         //  4 MB  [2048][1024]
    ushort_t* woutt = wqkvt + (size_t)QKV_N * DMODEL;        //  2 MB  [1024][1024]
    ushort_t* qkv   = woutt + (size_t)DMODEL * DMODEL;       // 16 MB  [4096][2048]
    ushort_t* z     = qkv   + (size_t)NTOK * QKV_N;          //  8 MB  [4096][1024]
    ushort_t* vt    = rbf;   // alias: rbf dead after qkv_gemm; tr_v runs later

    cvt_resid<<<dim3(NTOK * DMODEL / 1024), 256, 0, stream>>>(resid, rbf);
    tr_wqkv  <<<dim3(16, 32), 256, 0, stream>>>(Wq, Wk, Wv, wqkvt);
    tr_wout  <<<dim3(16, 16), 256, 0, stream>>>(Wout, woutt);
    qkv_gemm <<<dim3(16, 32), 256, 0, stream>>>(rbf, wqkvt, qkv);
    tr_v     <<<dim3(SEQ / 64, NGROUPS, BATCH), 256, 0, stream>>>(qkv, vt);
    attn     <<<dim3(16, NHEADS, BATCH), 256, 0, stream>>>(qkv, vt, z);
    out_gemm <<<dim3(8, 32), 256, 0, stream>>>(z, woutt, bout, out);
}